// Round 8
// baseline (502.131 us; speedup 1.0000x reference)
//
#include <hip/hip_runtime.h>
#include <hip/hip_cooperative_groups.h>

namespace cg = cooperative_groups;

// Restriction: h_coarse = R @ x_fine, R in COO (rows, cols, vals).
// Round 8: ONE cooperative kernel (was 5 dispatches).
//   phase 0: zero counts/ovf_cnt (replaces hipMemsetAsync)
//   phase 1: scatter edges -> cap-16 bins, overflow -> exact list
//   phase 2: wave-per-row gather, MLP-8, one 512B write per row
//   phase 3: exact atomic fallback for overflow edges (~600 @ lambda=8)
// grid.sync() = device-scope fence (cross-XCD visibility of counts/bins).
// Grid 1024x256 (4 blocks/CU @ 8 VGPR) -> co-residency guaranteed.
// Known fixed floor inside dur_us: ~60us ws-poison fill + ~5us d_out fill
// + ~35us d_in restore. This round targets the ~100us of our own work.

#define F    128
#define CAP  16
#define NBLK 1024
#define NTHR 256

__global__ __launch_bounds__(NTHR) void fused_restrict(
    const float* __restrict__ x_fine,
    const float* __restrict__ r_vals,
    const int*   __restrict__ r_rows,
    const int*   __restrict__ r_cols,
    float*       __restrict__ out,
    int*         __restrict__ counts,
    int2*        __restrict__ bins,
    int*         __restrict__ ovf_cnt,
    int3*        __restrict__ ovf,
    int nnz, int n_rows)
{
    cg::grid_group grid = cg::this_grid();
    const int tid = blockIdx.x * NTHR + threadIdx.x;
    const int nth = NBLK * NTHR;

    // ---- phase 0: init (ws is poisoned 0xAA before every call) ----
    for (int i = tid; i < n_rows; i += nth) counts[i] = 0;
    if (tid == 0) *ovf_cnt = 0;
    grid.sync();

    // ---- phase 1: scatter edges into fixed-capacity bins ----
    for (int i = tid; i < nnz; i += nth) {
        int   r = __builtin_nontemporal_load(r_rows + i);
        int   c = __builtin_nontemporal_load(r_cols + i);
        float v = __builtin_nontemporal_load(r_vals + i);
        int pos = atomicAdd(&counts[r], 1);
        if (pos < CAP) {
            bins[(size_t)r * CAP + pos] = make_int2(c, __float_as_int(v));
        } else {
            int p = atomicAdd(ovf_cnt, 1);
            ovf[p] = make_int3(r, c, __float_as_int(v));
        }
    }
    grid.sync();

    // ---- phase 2: gather, one 64-lane wave per row, MLP-8 ----
    const int wid  = tid >> 6;
    const int lane = tid & 63;
    const int nwaves = nth >> 6;
    const float2* xf = reinterpret_cast<const float2*>(x_fine);
    for (int row = wid; row < n_rows; row += nwaves) {
        int deg = counts[row];
        if (deg > CAP) deg = CAP;

        // One coalesced 128B edge load; zero-pad in registers so the blind
        // group-of-8 loop is exact (pad col=0,val=0 -> adds 0*row0).
        int2 e = make_int2(0, 0);
        if (lane < deg) e = bins[(size_t)row * CAP + lane];

        float2 acc = make_float2(0.f, 0.f);
        int deg8 = (deg + 7) & ~7;
        for (int j = 0; j < deg8; j += 8) {
            int   cc[8];
            float ww[8];
#pragma unroll
            for (int k = 0; k < 8; ++k) {
                cc[k] = __shfl(e.x, j + k);
                ww[k] = __int_as_float(__shfl(e.y, j + k));
            }
            float2 vv[8];
#pragma unroll
            for (int k = 0; k < 8; ++k)      // 8 independent 512B/wave loads
                vv[k] = xf[(size_t)cc[k] * 64 + lane];
#pragma unroll
            for (int k = 0; k < 8; ++k) {
                acc.x += ww[k] * vv[k].x;
                acc.y += ww[k] * vv[k].y;
            }
        }
        reinterpret_cast<float2*>(out)[(size_t)row * 64 + lane] = acc;
    }
    grid.sync();

    // ---- phase 3: exact fallback for overflow edges ----
    int n = *ovf_cnt;
    int total = n * 32;
    for (int idx = tid; idx < total; idx += nth) {
        int e32 = idx >> 5, q = idx & 31;
        int3 t = ovf[e32];
        float val = __int_as_float(t.z);
        float4 v = reinterpret_cast<const float4*>(x_fine + (size_t)t.y * F)[q];
        float* o = out + (size_t)t.x * F + q * 4;
        unsafeAtomicAdd(o + 0, v.x * val);
        unsafeAtomicAdd(o + 1, v.y * val);
        unsafeAtomicAdd(o + 2, v.z * val);
        unsafeAtomicAdd(o + 3, v.w * val);
    }
}

extern "C" void kernel_launch(void* const* d_in, const int* in_sizes, int n_in,
                              void* d_out, int out_size, void* d_ws, size_t ws_size,
                              hipStream_t stream) {
    const float* x_fine = (const float*)d_in[0];
    const float* r_vals = (const float*)d_in[1];
    const int*   r_rows = (const int*)d_in[2];
    const int*   r_cols = (const int*)d_in[3];
    float* out = (float*)d_out;

    int nnz    = in_sizes[1];
    int n_rows = out_size / F;

    // Workspace layout (byte offsets):
    //   0                : counts   (n_rows int)
    //   counts_b         : ovf_cnt  (1 int, padded to 16B)
    //   counts_b+16      : ovf      (nnz int3 = 12B each)
    //   counts_b+16+ovf_b: bins     (n_rows*CAP int2 = 6.4MB)
    size_t counts_b = (size_t)n_rows * 4;
    size_t ovf_b    = (size_t)nnz * 12;
    size_t fixed    = counts_b + 16 + ovf_b;

    char* ws = (char*)d_ws;
    int*  counts  = (int*)ws;
    int*  ovf_cnt = (int*)(ws + counts_b);
    int3* ovf     = (int3*)(ws + counts_b + 16);
    int2* bins    = (int2*)(ws + fixed);

    void* args[] = {
        (void*)&x_fine, (void*)&r_vals, (void*)&r_rows, (void*)&r_cols,
        (void*)&out, (void*)&counts, (void*)&bins, (void*)&ovf_cnt,
        (void*)&ovf, (void*)&nnz, (void*)&n_rows
    };
    hipLaunchCooperativeKernel((const void*)fused_restrict,
                               dim3(NBLK), dim3(NTHR), args, 0, stream);
}

// Round 11
// 202.206 us; speedup vs baseline: 2.4833x; 2.4833x over previous
//
#include <hip/hip_runtime.h>
#include <hip/hip_bf16.h>

// Restriction: h_coarse = R @ x_fine, R in COO (rows, cols, vals).
// Round 9 (3rd submit — rounds 9 and 10 both hit GPUAcquisitionTimeout):
// revert fusion (r8: coop launch capped TLP at 4096 waves -> 376us; split
// structure = 202us). Split kernels + gather dependency fix:
//   - Layout counts|ovf_cnt|bins contiguous; ONE memset zeroes all three
//     (6.6MB ~ 1.3us) -> bins rows are zero-padded (col=0,val=0).
//   - gather loads bins UNCONDITIONALLY (lane&15, no deg predicate) so the
//     bins load issues in parallel with the counts load (r7 had
//     counts -> predicated bins -> x_fine: 3 serial latencies; now 2).
//   - deg only sets trip count; padded entries add w=0 * row0 = exact.
// scatter_bins: cap-16 bins + exact overflow list (~600 edges @ lambda=8).
// ovf_apply: atomic fallback. Fixed floor inside dur_us: ~60us ws poison
// + ~5us out poison + ~35us d_in restore (harness, untouchable).

#define F   128
#define CAP 16

__global__ __launch_bounds__(256) void scatter_bins(
    const int*   __restrict__ rows, const int* __restrict__ cols,
    const float* __restrict__ vals,
    int* __restrict__ counts, int2* __restrict__ bins,
    int* __restrict__ ovf_cnt, int3* __restrict__ ovf, int nnz)
{
    int i = blockIdx.x * blockDim.x + threadIdx.x;
    if (i >= nnz) return;
    // Streaming reads (no reuse) — keep them out of L2's way.
    int   r = __builtin_nontemporal_load(rows + i);
    int   c = __builtin_nontemporal_load(cols + i);
    float v = __builtin_nontemporal_load(vals + i);
    int pos = atomicAdd(&counts[r], 1);
    if (pos < CAP) {
        bins[(size_t)r * CAP + pos] = make_int2(c, __float_as_int(v));
    } else {
        int p = atomicAdd(ovf_cnt, 1);
        ovf[p] = make_int3(r, c, __float_as_int(v));
    }
}

// One 64-lane wave per coarse row; lane owns 2 features (float2).
// counts and bins loads issue in parallel (bins load is unconditional;
// rows are zero-padded by the memset, so padded slots contribute 0).
__global__ __launch_bounds__(256) void gather_rows(
    const float* __restrict__ x_fine, const int2* __restrict__ bins,
    const int* __restrict__ counts, float* __restrict__ out, int n_rows)
{
    int gid  = blockIdx.x * blockDim.x + threadIdx.x;
    int row  = gid >> 6;
    int lane = gid & 63;
    if (row >= n_rows) return;

    // Two INDEPENDENT loads — no predicate chain between them.
    int2 e  = bins[(size_t)row * CAP + (lane & (CAP - 1))];
    int deg = counts[row];
    if (deg > CAP) deg = CAP;

    const float2* xf = reinterpret_cast<const float2*>(x_fine);
    float2 acc = make_float2(0.f, 0.f);
    int deg8 = (deg + 7) & ~7;

    for (int j = 0; j < deg8; j += 8) {
        int   cc[8];
        float ww[8];
#pragma unroll
        for (int k = 0; k < 8; ++k) {
            cc[k] = __shfl(e.x, j + k);
            ww[k] = __int_as_float(__shfl(e.y, j + k));
        }
        float2 vv[8];
#pragma unroll
        for (int k = 0; k < 8; ++k)      // 8 independent 512B/wave loads
            vv[k] = xf[(size_t)cc[k] * 64 + lane];
#pragma unroll
        for (int k = 0; k < 8; ++k) {
            acc.x += ww[k] * vv[k].x;
            acc.y += ww[k] * vv[k].y;
        }
    }
    reinterpret_cast<float2*>(out)[(size_t)row * 64 + lane] = acc;
}

// Exact fallback for overflow edges (~600 expected at CAP=16).
__global__ __launch_bounds__(256) void ovf_apply(
    const float* __restrict__ x_fine, const int3* __restrict__ ovf,
    const int* __restrict__ ovf_cnt, float* __restrict__ out)
{
    int n = *ovf_cnt;
    int total = n * 32;
    for (int idx = blockIdx.x * blockDim.x + threadIdx.x; idx < total;
         idx += gridDim.x * blockDim.x) {
        int e = idx >> 5, q = idx & 31;
        int3 t = ovf[e];
        float val = __int_as_float(t.z);
        float4 v = reinterpret_cast<const float4*>(x_fine + (size_t)t.y * F)[q];
        float* o = out + (size_t)t.x * F + q * 4;
        unsafeAtomicAdd(o + 0, v.x * val);
        unsafeAtomicAdd(o + 1, v.y * val);
        unsafeAtomicAdd(o + 2, v.z * val);
        unsafeAtomicAdd(o + 3, v.w * val);
    }
}

extern "C" void kernel_launch(void* const* d_in, const int* in_sizes, int n_in,
                              void* d_out, int out_size, void* d_ws, size_t ws_size,
                              hipStream_t stream) {
    const float* x_fine = (const float*)d_in[0];
    const float* r_vals = (const float*)d_in[1];
    const int*   r_rows = (const int*)d_in[2];
    const int*   r_cols = (const int*)d_in[3];
    float* out = (float*)d_out;

    int nnz    = in_sizes[1];
    int n_rows = out_size / F;

    // Workspace layout (byte offsets) — counts|ovf_cnt|bins CONTIGUOUS so
    // one memset zeroes all three (bins zero-padding is load-bearing):
    //   0                 : counts  (n_rows int = 200KB)
    //   counts_b          : ovf_cnt (1 int, padded to 16B)
    //   counts_b+16       : bins    (n_rows*CAP int2 = 6.4MB)
    //   counts_b+16+bins_b: ovf     (nnz int3 = 4.8MB)
    size_t counts_b = (size_t)n_rows * 4;
    size_t bins_b   = (size_t)n_rows * CAP * 8;

    char* ws = (char*)d_ws;
    int*  counts  = (int*)ws;
    int*  ovf_cnt = (int*)(ws + counts_b);
    int2* bins    = (int2*)(ws + counts_b + 16);
    int3* ovf     = (int3*)(ws + counts_b + 16 + bins_b);

    hipMemsetAsync(counts, 0, counts_b + 16 + bins_b, stream);

    int b_nnz = (nnz + 255) / 256;
    hipLaunchKernelGGL(scatter_bins, dim3(b_nnz), dim3(256), 0, stream,
                       r_rows, r_cols, r_vals, counts, bins,
                       ovf_cnt, ovf, nnz);

    int b_rows = (int)(((size_t)n_rows * 64 + 255) / 256);
    hipLaunchKernelGGL(gather_rows, dim3(b_rows), dim3(256), 0, stream,
                       x_fine, bins, counts, out, n_rows);

    hipLaunchKernelGGL(ovf_apply, dim3(64), dim3(256), 0, stream,
                       x_fine, ovf, ovf_cnt, out);
}